// Round 5
// baseline (605.003 us; speedup 1.0000x reference)
//
#include <hip/hip_runtime.h>
#include <hip/hip_bf16.h>

#define B_ 4096
#define T_ 2
#define S_ 4
#define E_ 128
#define NF_ 11
#define ID_ 55
#define MID_ 4
#define NG_ 6
#define SI_ 4
#define EPSf 1e-5f

// triu_indices(11, k=1) pairs, extended with a 56th zero-row entry (row 11 of s_fld is zeroed)
__device__ const int PR[56]={0,0,0,0,0,0,0,0,0,0,1,1,1,1,1,1,1,1,1,2,2,2,2,2,2,2,2,3,3,3,3,3,3,3,4,4,4,4,4,4,5,5,5,5,5,6,6,6,6,7,7,7,8,8,9,11};
__device__ const int PC[56]={1,2,3,4,5,6,7,8,9,10,2,3,4,5,6,7,8,9,10,3,4,5,6,7,8,9,10,4,5,6,7,8,9,10,5,6,7,8,9,10,6,7,8,9,10,7,8,9,10,8,9,10,9,10,10,11};

// -------- prep: Wu/lWu [64 rows][128 k]; transposed user/item weights -------
// Wu rows 0-47: gate E-part; 48-61: sb_W; 62-63: zero
__global__ void k_prep(const float* __restrict__ gW, const float* __restrict__ lgW,
                       const float* __restrict__ sbW, const float* __restrict__ lsbW,
                       const float* __restrict__ uW, const float* __restrict__ iW,
                       const float* __restrict__ ulW, const float* __restrict__ ilW,
                       float* __restrict__ Wu, float* __restrict__ lWu,
                       float* __restrict__ uWt, float* __restrict__ iWt,
                       float* __restrict__ ulWt, float* __restrict__ ilWt){
  int k = blockIdx.x*256 + threadIdx.x;
  if (k < 16384){
    int arr = k >> 13, rem = k & 8191;
    int o = rem >> 7, e = rem & 127;
    const float* g = arr ? lgW : gW;
    const float* s = arr ? lsbW : sbW;
    float v;
    if (o < 48) v = g[o*132 + 4 + e];
    else if (o < 62) v = s[(o-48)*128 + e];
    else v = 0.f;
    (arr ? lWu : Wu)[o*128 + e] = v;
  } else if (k < 16384 + 5888){           // uWt / ulWt : 23*128 each
    int r = k - 16384; int arr = r >= 2944; r -= arr*2944;
    int kk = r >> 7, e = r & 127;
    (arr ? ulWt : uWt)[kk*128+e] = (arr ? ulW : uW)[e*23+kk];
  } else if (k < 16384 + 5888 + 10240){   // iWt / ilWt : 40*128 each
    int r = k - 16384 - 5888; int arr = r >= 5120; r -= arr*5120;
    int kk = r >> 7, e = r & 127;
    (arr ? ilWt : iWt)[kk*128+e] = (arr ? ilW : iW)[e*40+kk];
  }
}

// -------- moe1: fields(gather+proj) -> GEMM (gate+ein) -> experts -> w_g ----
__global__ __launch_bounds__(256,3) void k_moe1(
    const int* __restrict__ cat, const float* __restrict__ num,
    const float* __restrict__ embT,
    const float* __restrict__ uWt, const float* __restrict__ ub,
    const float* __restrict__ iWt, const float* __restrict__ ib,
    const float* __restrict__ scen_emb, const float* __restrict__ task_emb,
    const float* __restrict__ st_w, const float* __restrict__ interact_w,
    const float* __restrict__ sb_b,
    const float* __restrict__ shexp_W, const float* __restrict__ shexp_b,
    const float* __restrict__ spexp_W, const float* __restrict__ spexp_b,
    const float* __restrict__ gate_W, const float* __restrict__ gate_b,
    const float* __restrict__ Wu,
    float* __restrict__ fields, float* __restrict__ w_g)
{
  __shared__ float s_fld[12*132];
  __shared__ float s_C[56*68];
  __shared__ float s_w[1760];
  __shared__ float s_sh[880];
  __shared__ float s_stig[48];
  __shared__ float s_iw[56];
  __shared__ float s_num[64];
  __shared__ float s_sbb[14];
  __shared__ float s_shw[224];
  __shared__ float s_shb[16];
  __shared__ float s_spw[896];
  __shared__ float s_spb[64];
  const int tid = threadIdx.x, b = blockIdx.x;
  const int scen = cat[(size_t)b*10];

  // phase 1: staging
  if (tid < 63) s_num[tid] = num[(size_t)b*63 + tid];
  for (int idx = tid; idx < 1152; idx += 256){
    int j = idx >> 7, e = idx & 127;
    int id = cat[(size_t)b*10 + 1 + j] + j*1000;
    s_fld[j*132+e] = embT[(size_t)id*128+e];
  }
  if (tid < 56) s_iw[tid] = (tid < 55) ? interact_w[tid] : 0.f;
  if (tid < 14) s_sbb[tid] = sb_b[tid];
  if (tid < 16) s_shb[tid] = shexp_b[tid];
  if (tid < 64) s_spb[tid] = spexp_b[tid];
  for (int idx = tid; idx < 224; idx += 256) s_shw[idx] = shexp_W[idx];
  for (int idx = tid; idx < 896; idx += 256) s_spw[idx] = spexp_W[idx];
  if (tid < 48){
    int t = (tid/6)%T_;
    float stw = st_w[t*S_ + scen];
    float acc = gate_b[tid];
    for (int i = 0; i < 4; ++i){
      float sti = scen_emb[scen*4+i] * task_emb[t*4+i] * stw;
      acc += sti * gate_W[tid*132 + i];
    }
    s_stig[tid] = acc;
  }
  __syncthreads();
  // user/item projections -> rows 9,10 ; zero row 11
  if (tid < 128){
    int e = tid;
    float a0 = ub[e];
    for (int k = 0; k < 23; ++k) a0 += s_num[k]*uWt[k*128+e];
    s_fld[9*132+e] = a0;
    s_fld[11*132+e] = 0.f;
  } else {
    int e = tid-128;
    float a2 = ib[e];
    for (int k = 0; k < 40; ++k) a2 += s_num[23+k]*iWt[k*128+e];
    s_fld[10*132+e] = a2;
  }
  __syncthreads();
  // write fields to global (for k_inter)
  for (int idx = tid; idx < 352; idx += 256){
    int f = idx >> 5, q = idx & 31;
    *(float4*)&fields[(size_t)b*1408 + f*128 + q*4] = *(float4*)&s_fld[f*132 + q*4];
  }
  // GEMM: C[56][64] = (fld_r * fld_c)[56][128] x Wu^T ; K 4-way split over lanes
  {
    const int lane = tid & 63, wv_ = tid >> 6;
    const int pair = wv_*16 + (lane & 15);
    const int ks = lane >> 4;
    const int ft = pair & 7, ot = pair >> 3;
    const int r0 = ft*7, k0 = ks*32;
    int pr[7], pc[7];
    for (int r = 0; r < 7; ++r){ pr[r] = PR[r0+r]*132; pc[r] = PC[r0+r]*132; }
    float acc[7][8];
    for (int r = 0; r < 7; ++r) for (int c = 0; c < 8; ++c) acc[r][c] = 0.f;
    const float4* Wu4 = (const float4*)Wu;
    #pragma unroll 1
    for (int kc = 0; kc < 32; kc += 4){
      int kk = k0 + kc;
      float4 a[7], wvv[8];
      for (int r = 0; r < 7; ++r){
        float4 x = *(const float4*)&s_fld[pr[r] + kk];
        float4 y = *(const float4*)&s_fld[pc[r] + kk];
        a[r].x = x.x*y.x; a[r].y = x.y*y.y; a[r].z = x.z*y.z; a[r].w = x.w*y.w;
      }
      for (int c = 0; c < 8; ++c) wvv[c] = Wu4[(ot*8+c)*32 + (kk>>2)];
      for (int r = 0; r < 7; ++r)
        for (int c = 0; c < 8; ++c)
          acc[r][c] += a[r].x*wvv[c].x + a[r].y*wvv[c].y + a[r].z*wvv[c].z + a[r].w*wvv[c].w;
    }
    for (int r = 0; r < 7; ++r) for (int c = 0; c < 8; ++c){
      float v = acc[r][c];
      v += __shfl_xor(v, 16); v += __shfl_xor(v, 32);
      acc[r][c] = v;
    }
    if (ks == 0){
      for (int r = 0; r < 7; ++r){
        int row = r0 + r;
        float iw = s_iw[row];
        for (int c = 0; c < 8; ++c){
          int col = ot*8 + c;
          float bias = (col < 48) ? s_stig[col] : ((col < 62) ? s_sbb[col-48] : 0.f);
          s_C[row*68 + col] = acc[r][c]*iw + bias;
        }
      }
    }
  }
  __syncthreads();
  // shared experts
  for (int o = tid; o < 880; o += 256){
    int f = o >> 4, j = o & 15;
    float acc = s_shb[j];
    for (int i = 0; i < 14; ++i) acc += s_C[f*68 + 48 + i] * s_shw[j*14+i];
    s_sh[o] = acc;
  }
  __syncthreads();
  // softmax + specific experts + mixture
  for (int task = tid; task < 440; task += 256){
    int st = task / 55, f = task % 55;
    float lg[6], mx = -1e30f;
    for (int g = 0; g < 6; ++g){ lg[g] = s_C[f*68 + st*6 + g]; mx = fmaxf(mx, lg[g]); }
    float sum = 0.f;
    for (int g = 0; g < 6; ++g){ lg[g] = __expf(lg[g]-mx); sum += lg[g]; }
    float inv = 1.f/sum;
    float wv[4] = {0,0,0,0};
    for (int g = 0; g < 4; ++g){
      float gg = lg[g]*inv;
      for (int m = 0; m < 4; ++m) wv[m] += gg * s_sh[f*16 + g*4 + m];
    }
    for (int ee = 0; ee < 2; ++ee){
      float gg = lg[4+ee]*inv;
      for (int m = 0; m < 4; ++m){
        float acc = s_spb[(st*2+ee)*4+m];
        const float* wp = s_spw + ((st*2+ee)*4+m)*14;
        for (int i = 0; i < 14; ++i) acc += s_C[f*68 + 48 + i] * wp[i];
        wv[m] += gg*acc;
      }
    }
    for (int m = 0; m < 4; ++m) s_w[st*220 + f*4 + m] = wv[m];
  }
  __syncthreads();
  // write w_g[b][st][224] (zero pad tail)
  for (int idx = tid; idx < 448; idx += 256){
    int st = idx / 56, q = idx % 56;
    float4 v;
    if (q < 55) v = *(float4*)&s_w[st*220 + q*4];
    else { v.x=v.y=v.z=v.w=0.f; }
    *(float4*)&w_g[((size_t)b*8 + st)*224 + q*4] = v;
  }
}

// -------- mask batch GEMM: m1[st*55+oo][b] = mW[st] x w^T + mb --------------
__global__ __launch_bounds__(256) void k_mask(
    const float* __restrict__ w_g, const float* __restrict__ mask_W,
    const float* __restrict__ mask_b, float* __restrict__ m1)
{
  __shared__ float s_mw[56*116];
  __shared__ float s_wb[64*116];
  const int tid = threadIdx.x;
  const int st = blockIdx.x >> 6, bt = blockIdx.x & 63;
  const int b0 = bt*64;
  const int btl = tid & 15, ot = tid >> 4;
  float acc[4][4];
  for (int c = 0; c < 4; ++c) for (int j = 0; j < 4; ++j) acc[c][j] = 0.f;

  for (int kc = 0; kc < 2; ++kc){
    __syncthreads();
    for (int idx = tid; idx < 64*112; idx += 256){
      int r = idx / 112, k = idx % 112;
      s_wb[r*116 + k] = w_g[((size_t)(b0+r)*8 + st)*224 + kc*112 + k];
    }
    for (int idx = tid; idx < 56*112; idx += 256){
      int r = idx / 112, k = idx % 112;
      int kg = kc*112 + k;
      s_mw[r*116 + k] = (r < 55 && kg < 220) ? mask_W[((size_t)st*55 + r)*220 + kg] : 0.f;
    }
    __syncthreads();
    if (ot < 14){
      for (int k4 = 0; k4 < 112; k4 += 4){
        float4 a[4], wb[4];
        for (int c = 0; c < 4; ++c) a[c]  = *(float4*)&s_mw[(ot*4+c)*116 + k4];
        for (int j = 0; j < 4; ++j) wb[j] = *(float4*)&s_wb[(btl*4+j)*116 + k4];
        for (int c = 0; c < 4; ++c)
          for (int j = 0; j < 4; ++j)
            acc[c][j] += a[c].x*wb[j].x + a[c].y*wb[j].y + a[c].z*wb[j].z + a[c].w*wb[j].w;
      }
    }
  }
  if (ot < 14){
    for (int c = 0; c < 4; ++c){
      int row = ot*4 + c;
      if (row < 55){
        float mb = mask_b[st*55 + row];
        float4 v; v.x = acc[c][0]+mb; v.y = acc[c][1]+mb; v.z = acc[c][2]+mb; v.w = acc[c][3]+mb;
        *(float4*)&m1[(size_t)(st*55+row)*B_ + b0 + btl*4] = v;
      }
    }
  }
}

// -------- per-row batch stats (mean, rsqrt(var+eps)) ------------------------
__global__ __launch_bounds__(256) void k_stats(const float* __restrict__ x, float* __restrict__ stats){
  const int row = blockIdx.x, tid = threadIdx.x;
  const float* xr = x + (size_t)row*B_;
  float s = 0.f, s2 = 0.f;
  for (int i = tid; i < B_; i += 256){ float v = xr[i]; s += v; s2 += v*v; }
  for (int off = 32; off > 0; off >>= 1){ s += __shfl_down(s, off); s2 += __shfl_down(s2, off); }
  __shared__ float red[8];
  if ((tid & 63) == 0){ red[(tid>>6)*2] = s; red[(tid>>6)*2+1] = s2; }
  __syncthreads();
  if (tid == 0){
    float Ssum = red[0]+red[2]+red[4]+red[6], S2 = red[1]+red[3]+red[5]+red[7];
    float mean = Ssum*(1.f/B_), var = S2*(1.f/B_) - mean*mean;
    stats[row*2] = mean; stats[row*2+1] = rsqrtf(fmaxf(var, 0.f) + EPSf);
  }
}

// -------- inter: bn(m)->tanh->relu, weighted pe contraction -> h[:, :128] ---
__global__ __launch_bounds__(128) void k_inter(
    const int* __restrict__ cat, const float* __restrict__ fields,
    const float* __restrict__ m1, const float* __restrict__ stm,
    const float* __restrict__ att_W, const float* __restrict__ interact_w,
    float* __restrict__ hbuf)
{
  __shared__ float s_fld[NF_*E_];
  __shared__ float s_co[110];
  const int b = blockIdx.x, e = threadIdx.x;
  const int scen = cat[(size_t)b*10];
  for (int k = e; k < NF_*E_; k += 128) s_fld[k] = fields[(size_t)b*NF_*E_ + k];
  if (e < 110){
    int t = e/55, f = e%55, row = (scen*T_+t)*55 + f;
    float v = (m1[(size_t)row*B_+b] - stm[row*2]) * stm[row*2+1];
    v = fmaxf(tanhf(v), 0.f);
    s_co[e] = v * att_W[(scen*T_+t)*55 + f];
  }
  __syncthreads();
  float a0 = 0.f, a1 = 0.f;
  for (int f = 0; f < 55; ++f){
    float pe = s_fld[PR[f]*E_+e] * s_fld[PC[f]*E_+e] * interact_w[f];
    a0 += s_co[f]*pe; a1 += s_co[55+f]*pe;
  }
  hbuf[(size_t)(0*256+e)*B_ + b] = a0;
  hbuf[(size_t)(1*256+e)*B_ + b] = a1;
}

// -------- moe2 (linear path): fused gather+proj+GEMM+experts+ltower ---------
__global__ __launch_bounds__(256) void k_moe2(
    const int* __restrict__ cat, const float* __restrict__ num,
    const float* __restrict__ linT,
    const float* __restrict__ ulWt, const float* __restrict__ ulb,
    const float* __restrict__ ilWt, const float* __restrict__ ilb,
    const float* __restrict__ scen_emb, const float* __restrict__ task_emb,
    const float* __restrict__ st_w,
    const float* __restrict__ lsb_b,
    const float* __restrict__ lshexp_W, const float* __restrict__ lshexp_b,
    const float* __restrict__ lspexp_W, const float* __restrict__ lspexp_b,
    const float* __restrict__ lgate_W, const float* __restrict__ lgate_b,
    const float* __restrict__ ltower_W, const float* __restrict__ ltower_b,
    const float* __restrict__ lWu,
    float* __restrict__ lfields, float* __restrict__ lt1)
{
  __shared__ float s_lf[12*132];
  __shared__ float s_C[12*68];
  __shared__ float s_w[352];
  __shared__ float s_sh[176];
  __shared__ float s_stig[48];
  __shared__ float s_num[64];
  __shared__ float s_lsbb[14];
  __shared__ float s_shw[224];
  __shared__ float s_shb[16];
  __shared__ float s_spw[896];
  __shared__ float s_spb[64];
  const int tid = threadIdx.x, b = blockIdx.x;
  const int scen = cat[(size_t)b*10];

  if (tid < 63) s_num[tid] = num[(size_t)b*63 + tid];
  for (int idx = tid; idx < 1152; idx += 256){
    int j = idx >> 7, e = idx & 127;
    int id = cat[(size_t)b*10 + 1 + j] + j*1000;
    s_lf[j*132+e] = linT[(size_t)id*128+e];
  }
  if (tid < 14) s_lsbb[tid] = lsb_b[tid];
  if (tid < 16) s_shb[tid] = lshexp_b[tid];
  if (tid < 64) s_spb[tid] = lspexp_b[tid];
  for (int idx = tid; idx < 224; idx += 256) s_shw[idx] = lshexp_W[idx];
  for (int idx = tid; idx < 896; idx += 256) s_spw[idx] = lspexp_W[idx];
  if (tid < 48){
    int t = (tid/6)%T_;
    float stw = st_w[t*S_ + scen];
    float acc = lgate_b[tid];
    for (int i = 0; i < 4; ++i){
      float sti = scen_emb[scen*4+i] * task_emb[t*4+i] * stw;
      acc += sti * lgate_W[tid*132 + i];
    }
    s_stig[tid] = acc;
  }
  __syncthreads();
  if (tid < 128){
    int e = tid;
    float a0 = ulb[e];
    for (int k = 0; k < 23; ++k) a0 += s_num[k]*ulWt[k*128+e];
    s_lf[9*132+e] = a0;
    s_lf[11*132+e] = 0.f;
  } else {
    int e = tid-128;
    float a2 = ilb[e];
    for (int k = 0; k < 40; ++k) a2 += s_num[23+k]*ilWt[k*128+e];
    s_lf[10*132+e] = a2;
  }
  __syncthreads();
  for (int idx = tid; idx < 352; idx += 256){
    int f = idx >> 5, q = idx & 31;
    *(float4*)&lfields[(size_t)b*1408 + f*128 + q*4] = *(float4*)&s_lf[f*132 + q*4];
  }
  // GEMM: all 256 threads. col = tid&63, rows rg*3..rg*3+2, full K.
  {
    const int col = tid & 63, rg = tid >> 6;
    float acc[3] = {0.f, 0.f, 0.f};
    const float4* W4 = (const float4*)lWu;
    for (int k4 = 0; k4 < 32; ++k4){
      float4 w = W4[col*32 + k4];
      for (int j = 0; j < 3; ++j){
        float4 a = *(const float4*)&s_lf[(rg*3+j)*132 + k4*4];
        acc[j] += a.x*w.x + a.y*w.y + a.z*w.z + a.w*w.w;
      }
    }
    float bias = (col < 48) ? s_stig[col] : ((col < 62) ? s_lsbb[col-48] : 0.f);
    for (int j = 0; j < 3; ++j) s_C[(rg*3+j)*68 + col] = acc[j] + bias;
  }
  __syncthreads();
  if (tid < 176){
    int f = tid >> 4, j = tid & 15;
    float acc = s_shb[j];
    for (int i = 0; i < 14; ++i) acc += s_C[f*68 + 48 + i] * s_shw[j*14+i];
    s_sh[tid] = acc;
  }
  __syncthreads();
  if (tid < 88){
    int st = tid / 11, f = tid % 11;
    float lg[6], mx = -1e30f;
    for (int g = 0; g < 6; ++g){ lg[g] = s_C[f*68 + st*6 + g]; mx = fmaxf(mx, lg[g]); }
    float sum = 0.f;
    for (int g = 0; g < 6; ++g){ lg[g] = __expf(lg[g]-mx); sum += lg[g]; }
    float inv = 1.f/sum;
    float wv[4] = {0,0,0,0};
    for (int g = 0; g < 4; ++g){
      float gg = lg[g]*inv;
      for (int m = 0; m < 4; ++m) wv[m] += gg * s_sh[f*16 + g*4 + m];
    }
    for (int ee = 0; ee < 2; ++ee){
      float gg = lg[4+ee]*inv;
      for (int m = 0; m < 4; ++m){
        float acc = s_spb[(st*2+ee)*4+m];
        const float* wp = s_spw + ((st*2+ee)*4+m)*14;
        for (int i = 0; i < 14; ++i) acc += s_C[f*68 + 48 + i] * wp[i];
        wv[m] += gg*acc;
      }
    }
    for (int m = 0; m < 4; ++m) s_w[st*44 + f*4 + m] = wv[m];
  }
  __syncthreads();
  if (tid < 88){
    int st = tid / 11, oo = tid % 11;
    float acc = ltower_b[st*11+oo];
    const float* tw = ltower_W + (st*11+oo)*44;
    const float* wp = s_w + st*44;
    for (int i = 0; i < 44; ++i) acc += wp[i] * tw[i];
    lt1[(size_t)(st*11+oo)*B_ + b] = acc;
  }
}

// -------- linf: bn(lt)->softmax over fields, weighted lfields -> h[:,128:] --
__global__ __launch_bounds__(128) void k_linf(
    const int* __restrict__ cat, const float* __restrict__ lfields,
    const float* __restrict__ lt1, const float* __restrict__ stl,
    const float* __restrict__ bias_p, float* __restrict__ hbuf)
{
  __shared__ float s_lf[NF_*E_];
  __shared__ float s_lw[22];
  const int b = blockIdx.x, e = threadIdx.x;
  const int scen = cat[(size_t)b*10];
  for (int k = e; k < NF_*E_; k += 128) s_lf[k] = lfields[(size_t)b*NF_*E_ + k];
  if (e < 22){
    int t = e/11, f = e%11, row = (scen*T_+t)*11 + f;
    s_lw[e] = (lt1[(size_t)row*B_+b] - stl[row*2]) * stl[row*2+1];
  }
  __syncthreads();
  if (e < 2){
    int t = e; float mx = -1e30f;
    for (int f = 0; f < 11; ++f) mx = fmaxf(mx, s_lw[t*11+f]);
    float sum = 0.f;
    for (int f = 0; f < 11; ++f){ float x = __expf(s_lw[t*11+f]-mx); s_lw[t*11+f] = x; sum += x; }
    float inv = 1.f/sum;
    for (int f = 0; f < 11; ++f) s_lw[t*11+f] *= inv;
  }
  __syncthreads();
  for (int t = 0; t < 2; ++t){
    float acc = bias_p[(size_t)(t*S_+scen)*E_ + e];
    for (int f = 0; f < 11; ++f) acc += s_lw[t*11+f] * s_lf[f*E_+e];
    hbuf[(size_t)(t*256+128+e)*B_ + b] = acc;
  }
}

// -------- final MLP ---------------------------------------------------------
__global__ __launch_bounds__(256) void k_last1(const float* __restrict__ hbuf,
    const float* __restrict__ W1, const float* __restrict__ b1, float* __restrict__ h1){
  int bz = blockIdx.x, t = bz/80, r = bz%80, og = r/16, bc = r%16;
  __shared__ float s_w1[8*256];
  int tid = threadIdx.x;
  for (int k = tid; k < 2048; k += 256){
    int oo = k>>8, i = k&255;
    s_w1[k] = W1[(size_t)(t*40 + og*8 + oo)*256 + i];
  }
  __syncthreads();
  int b = bc*256 + tid;
  float acc[8];
  for (int oo = 0; oo < 8; ++oo) acc[oo] = b1[t*40 + og*8 + oo];
  for (int i = 0; i < 256; ++i){
    float hv = hbuf[(size_t)(t*256+i)*B_ + b];
    for (int oo = 0; oo < 8; ++oo) acc[oo] += hv * s_w1[oo*256+i];
  }
  for (int oo = 0; oo < 8; ++oo) h1[(size_t)(t*40 + og*8 + oo)*B_ + b] = acc[oo];
}

__global__ __launch_bounds__(256) void k_last2(const float* __restrict__ h1, const float* __restrict__ st1,
    const float* __restrict__ W2, const float* __restrict__ b2v, float* __restrict__ h2){
  int bz = blockIdx.x, t = bz/16, bc = bz%16, tid = threadIdx.x, b = bc*256 + tid;
  __shared__ float s_w2[1280];
  for (int k = tid; k < 1280; k += 256) s_w2[k] = W2[t*1280 + k];
  __syncthreads();
  float hv[40];
  for (int i = 0; i < 40; ++i){
    int row = t*40 + i;
    hv[i] = fmaxf((h1[(size_t)row*B_+b] - st1[row*2]) * st1[row*2+1], 0.f);
  }
  for (int o = 0; o < 32; ++o){
    float acc = b2v[t*32+o];
    for (int i = 0; i < 40; ++i) acc += hv[i] * s_w2[o*40+i];
    h2[(size_t)(t*32+o)*B_ + b] = acc;
  }
}

__global__ __launch_bounds__(256) void k_last3(const float* __restrict__ h2, const float* __restrict__ st2,
    const float* __restrict__ W3, const float* __restrict__ b3v, float* __restrict__ h3){
  int bz = blockIdx.x, t = bz/16, bc = bz%16, tid = threadIdx.x, b = bc*256 + tid;
  __shared__ float s_w3[256];
  if (tid < 256) s_w3[tid] = W3[t*256 + tid];
  __syncthreads();
  float hv[32];
  for (int i = 0; i < 32; ++i){
    int row = t*32 + i;
    hv[i] = fmaxf((h2[(size_t)row*B_+b] - st2[row*2]) * st2[row*2+1], 0.f);
  }
  for (int o = 0; o < 8; ++o){
    float acc = b3v[t*8+o];
    for (int i = 0; i < 32; ++i) acc += hv[i] * s_w3[o*32+i];
    h3[(size_t)(t*8+o)*B_ + b] = acc;
  }
}

__global__ __launch_bounds__(256) void k_out(const float* __restrict__ h3, const float* __restrict__ st3,
    const float* __restrict__ W4, const float* __restrict__ b4v, float* __restrict__ out){
  int idx = blockIdx.x*256 + threadIdx.x;
  int t = idx / B_, b = idx % B_;
  float acc = b4v[t];
  for (int i = 0; i < 8; ++i){
    int row = t*8 + i;
    float v = fmaxf((h3[(size_t)row*B_+b] - st3[row*2]) * st3[row*2+1], 0.f);
    acc += v * W4[t*8+i];
  }
  out[idx] = 1.f/(1.f + __expf(-acc));
}

extern "C" void kernel_launch(void* const* d_in, const int* in_sizes, int n_in,
                              void* d_out, int out_size, void* d_ws, size_t ws_size,
                              hipStream_t stream)
{
  const int*   cat      = (const int*)  d_in[0];
  const float* num      = (const float*)d_in[1];
  const float* embT     = (const float*)d_in[2];
  const float* linT     = (const float*)d_in[3];
  const float* uW = (const float*)d_in[4];  const float* ub = (const float*)d_in[5];
  const float* iW = (const float*)d_in[6];  const float* ib = (const float*)d_in[7];
  const float* ulW = (const float*)d_in[8]; const float* ulb = (const float*)d_in[9];
  const float* ilW = (const float*)d_in[10];const float* ilb = (const float*)d_in[11];
  const float* scen_emb = (const float*)d_in[12];
  const float* task_emb = (const float*)d_in[13];
  const float* st_w     = (const float*)d_in[14];
  const float* interact_w=(const float*)d_in[15];
  const float* sbW = (const float*)d_in[16]; const float* sbb = (const float*)d_in[17];
  const float* lsbW = (const float*)d_in[18];const float* lsbb = (const float*)d_in[19];
  const float* shW = (const float*)d_in[20]; const float* shb = (const float*)d_in[21];
  const float* spW = (const float*)d_in[22]; const float* spb = (const float*)d_in[23];
  const float* lshW = (const float*)d_in[24];const float* lshb = (const float*)d_in[25];
  const float* lspW = (const float*)d_in[26];const float* lspb = (const float*)d_in[27];
  const float* gW = (const float*)d_in[28];  const float* gb = (const float*)d_in[29];
  const float* lgW = (const float*)d_in[30]; const float* lgb = (const float*)d_in[31];
  const float* mW = (const float*)d_in[32];  const float* mb = (const float*)d_in[33];
  const float* attW = (const float*)d_in[34];
  const float* ltW = (const float*)d_in[35]; const float* ltb = (const float*)d_in[36];
  const float* biasP = (const float*)d_in[37];
  const float* W1 = (const float*)d_in[38];  const float* b1 = (const float*)d_in[39];
  const float* W2 = (const float*)d_in[40];  const float* b2v = (const float*)d_in[41];
  const float* W3 = (const float*)d_in[42];  const float* b3v = (const float*)d_in[43];
  const float* W4 = (const float*)d_in[44];  const float* b4v = (const float*)d_in[45];
  float* out = (float*)d_out;

  float* ws = (float*)d_ws;
  size_t o = 0;
  float* fieldsB  = ws + o; o += (size_t)B_*NF_*E_;
  float* lfieldsB = ws + o; o += (size_t)B_*NF_*E_;
  float* Wu   = ws + o; o += 8192;
  float* lWu  = ws + o; o += 8192;
  float* uWt  = ws + o; o += 2944;
  float* iWt  = ws + o; o += 5120;
  float* ulWt = ws + o; o += 2944;
  float* ilWt = ws + o; o += 5120;
  float* w_g  = ws + o; o += (size_t)B_*8*224;
  float* m1   = ws + o; o += (size_t)440*B_;
  float* stm  = ws + o; o += 880;
  float* lt1  = ws + o; o += (size_t)88*B_;
  float* stl  = ws + o; o += 176;
  float* hbuf = ws + o; o += (size_t)T_*256*B_;
  float* h1   = ws + o; o += (size_t)80*B_;
  float* st1  = ws + o; o += 160;
  float* h2   = ws + o; o += (size_t)64*B_;
  float* st2  = ws + o; o += 128;
  float* h3   = ws + o; o += (size_t)16*B_;
  float* st3  = ws + o; o += 32;

  k_prep<<<127, 256, 0, stream>>>(gW, lgW, sbW, lsbW, uW, iW, ulW, ilW,
                                  Wu, lWu, uWt, iWt, ulWt, ilWt);
  k_moe1<<<B_, 256, 0, stream>>>(cat, num, embT, uWt, ub, iWt, ib,
                                 scen_emb, task_emb, st_w, interact_w,
                                 sbb, shW, shb, spW, spb, gW, gb, Wu,
                                 fieldsB, w_g);
  k_mask<<<512, 256, 0, stream>>>(w_g, mW, mb, m1);
  k_stats<<<440, 256, 0, stream>>>(m1, stm);
  k_inter<<<B_, 128, 0, stream>>>(cat, fieldsB, m1, stm, attW, interact_w, hbuf);
  k_moe2<<<B_, 256, 0, stream>>>(cat, num, linT, ulWt, ulb, ilWt, ilb,
                                 scen_emb, task_emb, st_w,
                                 lsbb, lshW, lshb, lspW, lspb, lgW, lgb,
                                 ltW, ltb, lWu, lfieldsB, lt1);
  k_stats<<<88, 256, 0, stream>>>(lt1, stl);
  k_linf<<<B_, 128, 0, stream>>>(cat, lfieldsB, lt1, stl, biasP, hbuf);
  k_last1<<<160, 256, 0, stream>>>(hbuf, W1, b1, h1);
  k_stats<<<80, 256, 0, stream>>>(h1, st1);
  k_last2<<<32, 256, 0, stream>>>(h1, st1, W2, b2v, h2);
  k_stats<<<64, 256, 0, stream>>>(h2, st2);
  k_last3<<<32, 256, 0, stream>>>(h2, st2, W3, b3v, h3);
  k_stats<<<16, 256, 0, stream>>>(h3, st3);
  k_out<<<32, 256, 0, stream>>>(h3, st3, W4, b4v, out);
}